// Round 5
// baseline (1915.521 us; speedup 1.0000x reference)
//
#include <hip/hip_runtime.h>
#include <cmath>

#define T_STEPS 512
#define BATCH   64
#define ISZ     512
#define HSZ     512
#define EXN     32768   // u64 words per ring slot (64 batches x 512)

// ---------------------------------------------------------------------------
// Tagged-word exchange (proven protocol): one atomic u64 = {tag=t+1, h bits}.
// ---------------------------------------------------------------------------
__device__ __forceinline__ void ex_store(unsigned long long* w, float h, unsigned tag) {
    union { float f; unsigned u; } c; c.f = h;
    const unsigned long long v = ((unsigned long long)tag << 32) | (unsigned long long)c.u;
    __hip_atomic_store(w, v, __ATOMIC_RELAXED, __HIP_MEMORY_SCOPE_AGENT);
}

// Volatile-asm 16B load (kept from round 4: harmless, pins initial load).
__device__ __forceinline__ float4 ld_pin_f4(const float* p) {
    float4 v;
    asm volatile("global_load_dwordx4 %0, %1, off" : "=v"(v) : "v"(p));
    return v;
}

// ---------------------------------------------------------------------------
// 16-k-segment dot for 2 output rows x 2 batches, merged butterfly over the
// 32 ksegs (lane bits 0..4): 6 shfls, depth 5. Lane kseg<4 ends with the
// full dot for row=(kseg>>1)&1, b=kseg&1 (replicated over kseg bits 2..4).
// src layout: float4[base + kseg*5 + i], batch stride 160 f4 (5-f4 slot pad).
// ---------------------------------------------------------------------------
__device__ __forceinline__ float dot2_fold(const float4 (&W)[2][4],
                                           const float4* __restrict__ src,
                                           int base4, int kseg) {
    const float4* s0 = src + base4 + kseg * 5;   // batch 0
    const float4* s1 = s0 + 160;                 // batch 1
    float A0 = 0.f, A1 = 0.f, B0 = 0.f, B1 = 0.f;
    #pragma unroll
    for (int i = 0; i < 4; ++i) {
        const float4 h0 = s0[i];
        const float4 h1 = s1[i];
        const float4 w0 = W[0][i], w1 = W[1][i];
        A0 = fmaf(w0.x, h0.x, A0); A0 = fmaf(w0.y, h0.y, A0);
        A0 = fmaf(w0.z, h0.z, A0); A0 = fmaf(w0.w, h0.w, A0);
        A1 = fmaf(w1.x, h0.x, A1); A1 = fmaf(w1.y, h0.y, A1);
        A1 = fmaf(w1.z, h0.z, A1); A1 = fmaf(w1.w, h0.w, A1);
        B0 = fmaf(w0.x, h1.x, B0); B0 = fmaf(w0.y, h1.y, B0);
        B0 = fmaf(w0.z, h1.z, B0); B0 = fmaf(w0.w, h1.w, B0);
        B1 = fmaf(w1.x, h1.x, B1); B1 = fmaf(w1.y, h1.y, B1);
        B1 = fmaf(w1.z, h1.z, B1); B1 = fmaf(w1.w, h1.w, B1);
    }
    const bool sb0 = (kseg & 1) != 0;   // batch select
    const bool sb1 = (kseg & 2) != 0;   // row select
    const float u0 = (sb0 ? B0 : A0) + __shfl_xor(sb0 ? A0 : B0, 1, 64);
    const float u1 = (sb0 ? B1 : A1) + __shfl_xor(sb0 ? A1 : B1, 1, 64);
    float z = (sb1 ? u1 : u0) + __shfl_xor(sb1 ? u0 : u1, 2, 64);
    z += __shfl_xor(z, 4, 64);
    z += __shfl_xor(z, 8, 64);
    z += __shfl_xor(z, 16, 64);
    return z;
}

// ---------------------------------------------------------------------------
// Fused RNN with 2-pair time-multiplexing. 256 WGs = 16 pairgroups(4 batches)
// x 16 j-slices(32 j), 512 threads, 1 WG/CU. Each step runs two sub-
// iterations (pair 0, pair 1): while pair 0's agent-scope exchange round-trip
// propagates through the coherence point (~L3; XCD swizzle proved it is NOT
// L2-local: round 2 cut FETCH 7x, time 0%), the WG computes pair 1 -- the 64
// batches are independent recurrences, so the serial chain (the measured
// ~2000cyc/step stall) is hidden behind the other pair's compute.
// hl/xs single-buffered: a full barrier separates last-read from next-write.
// ---------------------------------------------------------------------------
__global__ __launch_bounds__(512, 2) void rnn_fused(const float* __restrict__ x,
                                                    const float* __restrict__ wih,
                                                    const float* __restrict__ whh,
                                                    float* __restrict__ out,
                                                    unsigned long long* __restrict__ ex) {
    __shared__ __align__(16) float hls[2560];   // [2 pair][2 b][32 kseg][5 f4]
    __shared__ __align__(16) float xss[2560];   // [4 bx][32 kseg][5 f4]
    const float4* hl4 = (const float4*)hls;
    const float4* xs4 = (const float4*)xss;

    const int tid  = threadIdx.x;
    const int bid  = blockIdx.x;
    const int xcd  = bid & 7;             // XCD under round-robin dispatch
    const int ib   = bid >> 3;            // 0..31 within XCD
    const int pg   = xcd * 2 + (ib & 1);  // pairgroup 0..15 (2 clusters/XCD)
    const int g    = ib >> 1;             // j-slice 0..15
    const int kseg = tid & 31;            // 16-wide k segment
    const int jg   = tid >> 5;            // 0..15 -> 2 j rows each
    const int jb   = g * 32 + jg * 2;
    const int b0   = pg * 4;              // first batch of pairgroup

    // ---- weight micro-panels: 2 rows x 16 k of W_hh and W_ih (64 f32) ----
    float4 wh[2][4], wi[2][4];
    #pragma unroll
    for (int r = 0; r < 2; ++r) {
        const float* hr = whh + (size_t)(jb + r) * HSZ + kseg * 16;
        const float* ir = wih + (size_t)(jb + r) * ISZ + kseg * 16;
        #pragma unroll
        for (int i = 0; i < 4; ++i) {
            wh[r][i] = ld_pin_f4(hr + 4 * i);
            wi[r][i] = ld_pin_f4(ir + 4 * i);
        }
    }
    asm volatile("s_waitcnt vmcnt(0)" ::: "memory");
    __builtin_amdgcn_sched_barrier(0);

    // poll pointers: word k=tid for (pair, batch) of this pairgroup
    unsigned long long* exw00 = ex + (size_t)(b0 + 0) * 512 + tid;  // pair0 b0
    unsigned long long* exw01 = ex + (size_t)(b0 + 1) * 512 + tid;  // pair0 b1
    unsigned long long* exw10 = ex + (size_t)(b0 + 2) * 512 + tid;  // pair1 b0
    unsigned long long* exw11 = ex + (size_t)(b0 + 3) * 512 + tid;  // pair1 b1

    // hl scatter offset for polled word k=tid (float idx; +640 floats per b)
    const int whf = (tid >> 4) * 20 + ((tid >> 2) & 3) * 4 + (tid & 3);

    // x staging role: thread covers (bx, idx*4..+3), coalesced float4
    const int bx  = tid >> 7;             // 0..3
    const int idx = tid & 127;            // f4 index within row
    const int xf4 = bx * 160 + (idx >> 2) * 5 + (idx & 3);
    const float* xsrc = x + (size_t)(b0 + bx) * ISZ + idx * 4;

    // designated-lane roles (valid for kseg<4)
    const int bsel = kseg & 1;
    const int row  = (kseg >> 1) & 1;
    const int outj = jb + row;
    const int ob0  = b0 + bsel;           // pair 0 batch
    const int ob1  = b0 + 2 + bsel;       // pair 1 batch
    float* outp0 = out + (size_t)ob0 * HSZ + outj;                // + t*B*H
    float* outp1 = out + (size_t)ob1 * HSZ + outj;
    unsigned long long* exs0 = ex + (size_t)ob0 * 512 + outj;     // + slot*EXN
    unsigned long long* exs1 = ex + (size_t)ob1 * 512 + outj;

    // ---- prologue: stage x(0), compute xw(0) for both pairs ----
    ((float4*)xss)[xf4] = *(const float4*)xsrc;
    __syncthreads();
    float xw0 = dot2_fold(wi, xs4, 0,   kseg);
    float xw1 = dot2_fold(wi, xs4, 320, kseg);

    for (int t = 0; t < T_STEPS; ++t) {
        const bool havex = (t < T_STEPS - 1);

        // issue x(t+1) prefetch at step top: consumed just before barrier B
        float4 xv;
        if (havex) xv = *(const float4*)(xsrc + (size_t)(t + 1) * (BATCH * ISZ));

        const size_t soff = (size_t)((t - 1) & 1) * EXN;

        // ================= sub-iteration: PAIR 0 =================
        if (t > 0) {
            unsigned long long v0 = __hip_atomic_load(exw00 + soff, __ATOMIC_RELAXED,
                                                      __HIP_MEMORY_SCOPE_AGENT);
            unsigned long long v1 = __hip_atomic_load(exw01 + soff, __ATOMIC_RELAXED,
                                                      __HIP_MEMORY_SCOPE_AGENT);
            while ((unsigned)(v0 >> 32) != (unsigned)t ||
                   (unsigned)(v1 >> 32) != (unsigned)t) {
                __builtin_amdgcn_s_sleep(1);
                v0 = __hip_atomic_load(exw00 + soff, __ATOMIC_RELAXED,
                                       __HIP_MEMORY_SCOPE_AGENT);
                v1 = __hip_atomic_load(exw01 + soff, __ATOMIC_RELAXED,
                                       __HIP_MEMORY_SCOPE_AGENT);
            }
            union { unsigned u; float f; } c0, c1;
            c0.u = (unsigned)v0; c1.u = (unsigned)v1;
            hls[whf]       = c0.f;
            hls[640 + whf] = c1.f;
        }
        __syncthreads();                               // barrier A

        {
            float acc = 0.f;
            if (t > 0) acc = dot2_fold(wh, hl4, 0, kseg);
            if (kseg < 4) {
                const float a2 = acc + xw0;
                const float e  = __expf(2.f * a2);     // tanh=(e-1)/(e+1)
                const float hv = 1.f - 2.f / (e + 1.f);
                outp0[(size_t)t * (BATCH * HSZ)] = hv;
                if (havex)
                    ex_store(exs0 + (size_t)(t & 1) * EXN, hv, (unsigned)(t + 1));
                else
                    out[(size_t)T_STEPS * BATCH * HSZ + (size_t)ob0 * HSZ + outj] = hv;
            }
        }

        // ================= sub-iteration: PAIR 1 =================
        if (t > 0) {
            unsigned long long v0 = __hip_atomic_load(exw10 + soff, __ATOMIC_RELAXED,
                                                      __HIP_MEMORY_SCOPE_AGENT);
            unsigned long long v1 = __hip_atomic_load(exw11 + soff, __ATOMIC_RELAXED,
                                                      __HIP_MEMORY_SCOPE_AGENT);
            while ((unsigned)(v0 >> 32) != (unsigned)t ||
                   (unsigned)(v1 >> 32) != (unsigned)t) {
                __builtin_amdgcn_s_sleep(1);
                v0 = __hip_atomic_load(exw10 + soff, __ATOMIC_RELAXED,
                                       __HIP_MEMORY_SCOPE_AGENT);
                v1 = __hip_atomic_load(exw11 + soff, __ATOMIC_RELAXED,
                                       __HIP_MEMORY_SCOPE_AGENT);
            }
            union { unsigned u; float f; } c0, c1;
            c0.u = (unsigned)v0; c1.u = (unsigned)v1;
            hls[1280 + whf] = c0.f;
            hls[1920 + whf] = c1.f;
        }
        if (havex) ((float4*)xss)[xf4] = xv;           // x(t+1): write-before-B,
        __syncthreads();                               // barrier B   read-after-B

        {
            float acc = 0.f;
            if (t > 0) acc = dot2_fold(wh, hl4, 320, kseg);
            if (kseg < 4) {
                const float a2 = acc + xw1;
                const float e  = __expf(2.f * a2);
                const float hv = 1.f - 2.f / (e + 1.f);
                outp1[(size_t)t * (BATCH * HSZ)] = hv;
                if (havex)
                    ex_store(exs1 + (size_t)(t & 1) * EXN, hv, (unsigned)(t + 1));
                else
                    out[(size_t)T_STEPS * BATCH * HSZ + (size_t)ob1 * HSZ + outj] = hv;
            }
        }

        // xw(t+1) for both pairs: off-chain, covers the stores' propagation
        if (havex) {
            xw0 = dot2_fold(wi, xs4, 0,   kseg);
            xw1 = dot2_fold(wi, xs4, 320, kseg);
        }
    }
}

// ---------------------------------------------------------------------------
extern "C" void kernel_launch(void* const* d_in, const int* in_sizes, int n_in,
                              void* d_out, int out_size, void* d_ws, size_t ws_size,
                              hipStream_t stream) {
    (void)in_sizes; (void)n_in; (void)out_size; (void)ws_size;
    const float* x   = (const float*)d_in[0];   // (512,64,512)
    const float* wih = (const float*)d_in[1];   // (512,512)
    const float* whh = (const float*)d_in[2];   // (512,512)
    float*       out = (float*)d_out;           // h_all (T,B,H) ++ h_last (B,H)
    unsigned long long* ex = (unsigned long long*)d_ws;   // 2*EXN u64 = 512 KB

    // zero the exchange tags (harness poisons d_ws each launch)
    (void)hipMemsetAsync(d_ws, 0, 2 * EXN * sizeof(unsigned long long), stream);

    hipLaunchKernelGGL(rnn_fused, dim3(256), dim3(512), 0, stream,
                       x, wih, whh, out, ex);
}

// Round 7
// 1164.503 us; speedup vs baseline: 1.6449x; 1.6449x over previous
//
#include <hip/hip_runtime.h>
#include <cmath>

#define T_STEPS 512
#define BATCH   64
#define ISZ     512
#define HSZ     512
#define EXN     32768   // u64 words per ring slot (64 batches x 512)

// ---------------------------------------------------------------------------
// Tagged-word exchange (proven protocol): one atomic u64 = {tag=t+1, h bits}.
// ---------------------------------------------------------------------------
__device__ __forceinline__ void ex_store(unsigned long long* w, float h, unsigned tag) {
    union { float f; unsigned u; } c; c.f = h;
    const unsigned long long v = ((unsigned long long)tag << 32) | (unsigned long long)c.u;
    __hip_atomic_store(w, v, __ATOMIC_RELAXED, __HIP_MEMORY_SCOPE_AGENT);
}

// Volatile-asm 16B load: pins the loaded value in the register file (cannot
// be remat'd/duplicated). BUDGET RULE (R6 post-mortem): max 128 pinned
// floats/thread at __launch_bounds__(512,2) -- 256 made RA infeasible and
// aborted the build. Phases A/B therefore time-share ONE 128-float array.
__device__ __forceinline__ float4 ld_pin_f4(const float* p) {
    float4 v;
    asm volatile("global_load_dwordx4 %0, %1, off" : "=v"(v) : "v"(p));
    return v;
}

// ---------------------------------------------------------------------------
// 16-k-segment dot for 8 output rows x 1 batch, merging butterfly over the
// 32 ksegs (lane bits 0..4): 9 shfls, depth 5. ALL lanes end with the full
// dot for row = kseg&7 (replicated over kseg bits 3..4); designated lanes
// kseg<8 have row = kseg. 3-level extension of the R4-proven 2-level pattern.
// src layout: float4[base + kseg*5 + i] (5-f4 slot pad, 2-way bank alias).
// ---------------------------------------------------------------------------
__device__ __forceinline__ float dot8_fold(const float4 (&W)[8][4],
                                           const float4* __restrict__ src,
                                           int base4, int kseg) {
    const float4* s = src + base4 + kseg * 5;
    float a0 = 0.f, a1 = 0.f, a2 = 0.f, a3 = 0.f;
    float a4 = 0.f, a5 = 0.f, a6 = 0.f, a7 = 0.f;
    #pragma unroll
    for (int i = 0; i < 4; ++i) {
        const float4 h = s[i];
        a0 = fmaf(W[0][i].x, h.x, a0); a0 = fmaf(W[0][i].y, h.y, a0);
        a0 = fmaf(W[0][i].z, h.z, a0); a0 = fmaf(W[0][i].w, h.w, a0);
        a1 = fmaf(W[1][i].x, h.x, a1); a1 = fmaf(W[1][i].y, h.y, a1);
        a1 = fmaf(W[1][i].z, h.z, a1); a1 = fmaf(W[1][i].w, h.w, a1);
        a2 = fmaf(W[2][i].x, h.x, a2); a2 = fmaf(W[2][i].y, h.y, a2);
        a2 = fmaf(W[2][i].z, h.z, a2); a2 = fmaf(W[2][i].w, h.w, a2);
        a3 = fmaf(W[3][i].x, h.x, a3); a3 = fmaf(W[3][i].y, h.y, a3);
        a3 = fmaf(W[3][i].z, h.z, a3); a3 = fmaf(W[3][i].w, h.w, a3);
        a4 = fmaf(W[4][i].x, h.x, a4); a4 = fmaf(W[4][i].y, h.y, a4);
        a4 = fmaf(W[4][i].z, h.z, a4); a4 = fmaf(W[4][i].w, h.w, a4);
        a5 = fmaf(W[5][i].x, h.x, a5); a5 = fmaf(W[5][i].y, h.y, a5);
        a5 = fmaf(W[5][i].z, h.z, a5); a5 = fmaf(W[5][i].w, h.w, a5);
        a6 = fmaf(W[6][i].x, h.x, a6); a6 = fmaf(W[6][i].y, h.y, a6);
        a6 = fmaf(W[6][i].z, h.z, a6); a6 = fmaf(W[6][i].w, h.w, a6);
        a7 = fmaf(W[7][i].x, h.x, a7); a7 = fmaf(W[7][i].y, h.y, a7);
        a7 = fmaf(W[7][i].z, h.z, a7); a7 = fmaf(W[7][i].w, h.w, a7);
    }
    const bool sb0 = (kseg & 1) != 0;   // row bit 0
    const bool sb1 = (kseg & 2) != 0;   // row bit 1
    const bool sb2 = (kseg & 4) != 0;   // row bit 2
    const float u0 = (sb0 ? a1 : a0) + __shfl_xor(sb0 ? a0 : a1, 1, 64);
    const float u1 = (sb0 ? a3 : a2) + __shfl_xor(sb0 ? a2 : a3, 1, 64);
    const float u2 = (sb0 ? a5 : a4) + __shfl_xor(sb0 ? a4 : a5, 1, 64);
    const float u3 = (sb0 ? a7 : a6) + __shfl_xor(sb0 ? a6 : a7, 1, 64);
    const float v0 = (sb1 ? u1 : u0) + __shfl_xor(sb1 ? u0 : u1, 2, 64);
    const float v1 = (sb1 ? u3 : u2) + __shfl_xor(sb1 ? u2 : u3, 2, 64);
    float z = (sb2 ? v1 : v0) + __shfl_xor(sb2 ? v0 : v1, 4, 64);
    z += __shfl_xor(z, 8, 64);
    z += __shfl_xor(z, 16, 64);
    return z;
}

// ---------------------------------------------------------------------------
// Phase-split fused RNN: 256 WGs = 64 batches x 4 j-slices (128 j), 512 thr,
// 1 WG/CU. Thread (jg 0..15, kseg 0..31) owns 8 rows x 16 k x 1 batch.
// Phase A: pin W_ih (128 fl), compute xw(t) for ALL t into out[] (no inter-WG
//   deps; later overwritten by h of the same slice by the same threads).
// Phase B: reload the SAME register array with W_hh (disjoint lifetimes ->
//   RA reuse, stays within the proven 128-float pin budget) and run the
//   recurrence: single-word poll, 4 producers/consumer, 8 f4 LDS reads/step,
//   no in-loop xw dot (prefetched from out one step ahead).
// Skeleton per R4 (proven): tagged-word ring depth 2, parity-double-buffered
// LDS, one barrier/step, XCD-clustered batches (perf heuristic only).
// ---------------------------------------------------------------------------
__global__ __launch_bounds__(512, 2) void rnn_fused(const float* __restrict__ x,
                                                    const float* __restrict__ wih,
                                                    const float* __restrict__ whh,
                                                    float* __restrict__ out,
                                                    unsigned long long* __restrict__ ex) {
    __shared__ __align__(16) float st[1280];    // [2 par][32 kseg][5 f4]
    const float4* st4 = (const float4*)st;

    const int tid  = threadIdx.x;
    const int bid  = blockIdx.x;
    const int xcd  = bid & 7;             // XCD under round-robin dispatch
    const int ib   = bid >> 3;            // 0..31 within XCD
    const int b    = xcd * 8 + (ib & 7);  // batch 0..63 (8 batches/XCD)
    const int g    = ib >> 3;             // j-slice 0..3 (128 j each)
    const int kseg = tid & 31;            // 16-wide k segment
    const int jg   = tid >> 5;            // 0..15 -> 8 j rows each
    const int jb   = g * 128 + jg * 8;

    // LDS scatter offset for word k=tid: float idx (kseg'*20 + i*4 + comp)
    const int whf = (tid >> 4) * 20 + ((tid >> 2) & 3) * 4 + (tid & 3);

    // x staging: thread tid covers x[t, b, tid] (scalar, coalesced)
    const float* xcol = x + (size_t)b * ISZ + tid;

    // designated-lane roles (kseg<8 stores; row defined for all lanes)
    const int outj = jb + (kseg & 7);
    float* outp = out + (size_t)b * HSZ + outj;                 // + t*B*H
    unsigned long long* exw    = ex + (size_t)b * 512 + tid;    // poll word
    unsigned long long* exself = ex + (size_t)b * 512 + outj;   // + slot*EXN

    // ======================= PHASE A: xw = x @ W_ih^T =======================
    float4 w[8][4];
    #pragma unroll
    for (int r = 0; r < 8; ++r) {
        const float* ir = wih + (size_t)(jb + r) * ISZ + kseg * 16;
        #pragma unroll
        for (int i = 0; i < 4; ++i)
            w[r][i] = ld_pin_f4(ir + 4 * i);
    }
    asm volatile("s_waitcnt vmcnt(0)" ::: "memory");
    __builtin_amdgcn_sched_barrier(0);

    st[whf] = xcol[0];                     // stage x(0) into par 0
    __syncthreads();
    for (int t = 0; t < T_STEPS; ++t) {
        float xv = 0.f;
        if (t < T_STEPS - 1) xv = xcol[(size_t)(t + 1) * (BATCH * ISZ)];
        const float v = dot8_fold(w, st4, (t & 1) * 160, kseg);
        if (kseg < 8) outp[(size_t)t * (BATCH * HSZ)] = v;
        if (t < T_STEPS - 1) st[((t + 1) & 1) * 640 + whf] = xv;
        __syncthreads();                   // one barrier per iter (parity-safe)
    }

    // ================= PHASE B: recurrence with W_hh pinned =================
    asm volatile("" ::: "memory");
    #pragma unroll
    for (int r = 0; r < 8; ++r) {
        const float* hr = whh + (size_t)(jb + r) * HSZ + kseg * 16;
        #pragma unroll
        for (int i = 0; i < 4; ++i)
            w[r][i] = ld_pin_f4(hr + 4 * i);
    }
    asm volatile("s_waitcnt vmcnt(0)" ::: "memory");
    __builtin_amdgcn_sched_barrier(0);
    __syncthreads();                       // xw stores visible block-wide

    float xwv = outp[0];                   // xw(0), written by this WG

    for (int t = 0; t < T_STEPS; ++t) {
        const bool havex = (t < T_STEPS - 1);

        // prefetch xw(t+1) early: L2/HBM latency hides under the poll
        float xwn = 0.f;
        if (havex) xwn = outp[(size_t)(t + 1) * (BATCH * HSZ)];

        if (t > 0) {
            const size_t soff = (size_t)((t - 1) & 1) * EXN;
            unsigned long long v = __hip_atomic_load(exw + soff, __ATOMIC_RELAXED,
                                                     __HIP_MEMORY_SCOPE_AGENT);
            while ((unsigned)(v >> 32) != (unsigned)t) {
                __builtin_amdgcn_s_sleep(1);
                v = __hip_atomic_load(exw + soff, __ATOMIC_RELAXED,
                                      __HIP_MEMORY_SCOPE_AGENT);
            }
            union { unsigned u; float f; } c; c.u = (unsigned)v;
            st[(t & 1) * 640 + whf] = c.f;
        }
        __syncthreads();                   // single barrier per step

        float acc = 0.f;
        if (t > 0)
            acc = dot8_fold(w, st4, (t & 1) * 160, kseg);

        if (kseg < 8) {                    // 8 designated lanes / 32
            const float a2 = acc + xwv;
            const float e  = __expf(2.f * a2);     // tanh = (e-1)/(e+1)
            const float hv = 1.f - 2.f / (e + 1.f);
            outp[(size_t)t * (BATCH * HSZ)] = hv;  // overwrite xw(t) w/ h(t)
            if (havex)
                ex_store(exself + (size_t)(t & 1) * EXN, hv, (unsigned)(t + 1));
            else
                out[(size_t)T_STEPS * BATCH * HSZ + (size_t)b * HSZ + outj] = hv;
        }
        xwv = xwn;
    }
}

// ---------------------------------------------------------------------------
extern "C" void kernel_launch(void* const* d_in, const int* in_sizes, int n_in,
                              void* d_out, int out_size, void* d_ws, size_t ws_size,
                              hipStream_t stream) {
    (void)in_sizes; (void)n_in; (void)out_size; (void)ws_size;
    const float* x   = (const float*)d_in[0];   // (512,64,512)
    const float* wih = (const float*)d_in[1];   // (512,512)
    const float* whh = (const float*)d_in[2];   // (512,512)
    float*       out = (float*)d_out;           // h_all (T,B,H) ++ h_last (B,H)
    unsigned long long* ex = (unsigned long long*)d_ws;   // 2*EXN u64 = 512 KB

    // zero the exchange tags (harness poisons d_ws each launch)
    (void)hipMemsetAsync(d_ws, 0, 2 * EXN * sizeof(unsigned long long), stream);

    hipLaunchKernelGGL(rnn_fused, dim3(256), dim3(512), 0, stream,
                       x, wih, whh, out, ex);
}